// Round 8
// baseline (222.632 us; speedup 1.0000x reference)
//
#include <hip/hip_runtime.h>

typedef short sh8 __attribute__((ext_vector_type(8)));
typedef short sh4 __attribute__((ext_vector_type(4)));
typedef float f32x4 __attribute__((ext_vector_type(4)));
typedef float f32x16 __attribute__((ext_vector_type(16)));
typedef unsigned u32x4 __attribute__((ext_vector_type(4)));

extern "C" __device__ float __ocml_native_exp2_f32(float);

__device__ __forceinline__ short f2bf(float f) {
  unsigned u = __builtin_bit_cast(unsigned, f);
  u += 0x7fffu + ((u >> 16) & 1u);
  return (short)(u >> 16);
}

// async global->LDS, 16B per lane. LDS dest = wave-uniform base + lane*16.
__device__ __forceinline__ void gload16(const short* g, short* l) {
  __builtin_amdgcn_global_load_lds(
      (const __attribute__((address_space(1))) unsigned*)g,
      (__attribute__((address_space(3))) unsigned*)l, 16, 0, 0);
}

// counted-vmcnt barriers: wait own-wave loads down to N outstanding, then
// block barrier, then compiler memfence (no LDS access hoists above).
__device__ __forceinline__ void wait2_barrier() {
  asm volatile("s_waitcnt vmcnt(2)" ::: "memory");
  __builtin_amdgcn_s_barrier();
  asm volatile("" ::: "memory");
}
__device__ __forceinline__ void wait1_barrier() {
  asm volatile("s_waitcnt vmcnt(1)" ::: "memory");
  __builtin_amdgcn_s_barrier();
  asm volatile("" ::: "memory");
}
__device__ __forceinline__ void wait0_barrier() {
  asm volatile("s_waitcnt vmcnt(0)" ::: "memory");
  __builtin_amdgcn_s_barrier();
  asm volatile("" ::: "memory");
}

// bijective XCD-aware block swizzle (exact for any nwg; 8 XCDs)
__device__ __forceinline__ int xcd_swizzle(int bidl, int nwg) {
  int q = nwg >> 3, rr = nwg & 7;
  int xcd = bidl & 7, idx = bidl >> 3;
  return (xcd < rr ? xcd * (q + 1) : rr * (q + 1) + (xcd - rr) * q) + idx;
}

// ---------------- cast kernels ----------------
__global__ void cast_f32_bf16(const float* __restrict__ in, short* __restrict__ out, int n) {
  int i = (blockIdx.x * blockDim.x + threadIdx.x) * 4;
  if (i >= n) return;
  float4 f = *(const float4*)(in + i);
  sh4 o;
  o.x = f2bf(f.x); o.y = f2bf(f.y); o.z = f2bf(f.z); o.w = f2bf(f.w);
  *(sh4*)(out + i) = o;
}

// in: [K][Nn] fp32 -> out: [Nn][K] bf16. 64x64 tile via LDS: coalesced
// float4 reads, coalesced sh8 writes.
__global__ __launch_bounds__(256) void transpose_cast_t(
    const float* __restrict__ in, short* __restrict__ out, int K, int Nn) {
  __shared__ short Tl[64][72];
  const int t = threadIdx.x;
  const int n0 = blockIdx.x * 64, k0 = blockIdx.y * 64;
  const int kr0 = t >> 4;          // 0..15
  const int nc = (t & 15) * 4;     // 0..60
#pragma unroll
  for (int p = 0; p < 4; p++) {
    int kr = kr0 + p * 16;
    float4 f = *(const float4*)(in + (size_t)(k0 + kr) * Nn + n0 + nc);
    Tl[nc + 0][kr] = f2bf(f.x);
    Tl[nc + 1][kr] = f2bf(f.y);
    Tl[nc + 2][kr] = f2bf(f.z);
    Tl[nc + 3][kr] = f2bf(f.w);
  }
  __syncthreads();
  const int nr0 = t >> 3;          // 0..31
  const int kk = (t & 7) * 8;      // 0..56
#pragma unroll
  for (int p = 0; p < 2; p++) {
    int nr = nr0 + p * 32;
    *(sh8*)(out + (size_t)(n0 + nr) * K + k0 + kk) = *(const sh8*)&Tl[nr][kk];
  }
}

// ---------------- generic GEMM (proj): C[M,Nn] = A @ Bt^T + bias ----------
// 64x128 tile (grid 768 = 3 blocks/CU, balanced). A 3-buf (distance 2) +
// B 2-buf (distance 1, L2-resident weights): 28KB LDS. Per iter: {vmcnt(1);
// barrier; issue B(t+1), A(t+2); compute t}.
template <int OUTF32>
__global__ __launch_bounds__(256, 4) void gemm_bt(
    const short* __restrict__ A, const short* __restrict__ Bt,
    const float* __restrict__ bias, void* __restrict__ Cv,
    int M, int Nn, int K) {
  __shared__ short SMEM[14336];    // A: 3x2048 @0, B: 2x4096 @6144
  const int t = threadIdx.x;
  const int wave = t >> 6, lane = t & 63, quad = lane >> 4, l15 = lane & 15;
  const int wm = (wave >> 1) * 32, wn = (wave & 1) * 64;
  const int nwg = gridDim.x * gridDim.y;
  const int wg = xcd_swizzle(blockIdx.y * gridDim.x + blockIdx.x, nwg);
  const int row0 = (wg / gridDim.x) * 64, col0 = (wg % gridDim.x) * 128;
  f32x4 acc[2][4] = {};

  const int srow = t >> 2;                         // 0..63
  const int ssl = ((t & 3) ^ ((t >> 3) & 3)) * 8;
  const short* Asrc0 = A + (size_t)(row0 + srow) * K + ssl;
  const short* Bsrc0 = Bt + (size_t)(col0 + srow) * K + ssl;
  const short* Bsrc1 = Bt + (size_t)(col0 + 64 + srow) * K + ssl;
  short* AsF = SMEM;
  short* BsF = SMEM + 6144;
  const int wdst = wave * 512;

  const int soA = (quad ^ ((l15 >> 1) & 3)) * 8;

  const int T = K >> 5;
  // prologue: A0, B0, A1 (queue 4; iter0 vmcnt(1) keeps A1)
  gload16(Asrc0, AsF + wdst);
  gload16(Bsrc0, BsF + wdst);
  gload16(Bsrc1, BsF + 2048 + wdst);
  gload16(Asrc0 + 32, AsF + 2048 + wdst);

  int ra = 0, wa = 2;
  for (int tt = 0; tt < T; tt++) {
    if (tt + 1 < T) wait1_barrier(); else wait0_barrier();
    if (tt + 1 < T) {                    // B(t+1), distance 1
      const int k0 = (tt + 1) * 32;
      short* Bd = BsF + ((tt + 1) & 1) * 4096 + wdst;
      gload16(Bsrc0 + k0, Bd);
      gload16(Bsrc1 + k0, Bd + 2048);
    }
    if (tt + 2 < T) {                    // A(t+2), distance 2
      gload16(Asrc0 + (tt + 2) * 32, AsF + wa * 2048 + wdst);
    }
    const short* Ab = AsF + ra * 2048;
    const short* Bb = BsF + (tt & 1) * 4096;
    sh8 af[2], bfv[4];
#pragma unroll
    for (int i = 0; i < 2; i++) af[i] = *(const sh8*)&Ab[(wm + i * 16 + l15) * 32 + soA];
#pragma unroll
    for (int j = 0; j < 4; j++) bfv[j] = *(const sh8*)&Bb[(wn + j * 16 + l15) * 32 + soA];
#pragma unroll
    for (int i = 0; i < 2; i++)
#pragma unroll
      for (int j = 0; j < 4; j++)
        acc[i][j] = __builtin_amdgcn_mfma_f32_16x16x32_bf16(af[i], bfv[j], acc[i][j], 0, 0, 0);
    ra = ra == 2 ? 0 : ra + 1;
    wa = wa == 2 ? 0 : wa + 1;
  }

#pragma unroll
  for (int i = 0; i < 2; i++)
#pragma unroll
    for (int j = 0; j < 4; j++) {
      int r = row0 + wm + i * 16 + quad * 4;
      int c = col0 + wn + j * 16 + l15;
      float bv = bias[c];
#pragma unroll
      for (int e = 0; e < 4; e++) {
        float v = acc[i][j][e] + bv;
        if (OUTF32)
          ((float*)Cv)[(size_t)(r + e) * Nn + c] = v;
        else
          ((short*)Cv)[(size_t)(r + e) * Nn + c] = f2bf(v);
      }
    }
}

// ---------------- QKV GEMM with per-head scatter ----------------
// Writes Qh/Kh: [48][2048][64] bf16 and VhT: [48][64][2048] directly
// (V-transpose fused in epilogue). Q gets *(0.125*log2(e)) folded in.
// A3/B2 counted-vmcnt pipeline; 40KB LDS.
__global__ __launch_bounds__(256, 4) void gemm_qkv(
    const short* __restrict__ A, const short* __restrict__ Bt,
    const float* __restrict__ bias,
    short* __restrict__ Qh, short* __restrict__ Kh, short* __restrict__ VhT) {
  const int K = 768;
  __shared__ short SMEM[20480];    // staging 40KB / V-transpose Tl 34.8KB
  const int t = threadIdx.x;
  const int wave = t >> 6, lane = t & 63, quad = lane >> 4, l15 = lane & 15;
  const int wm = (wave >> 1) * 64, wn = (wave & 1) * 64;
  const int nwg = gridDim.x * gridDim.y;     // 18*64, %8==0
  const int wg = xcd_swizzle(blockIdx.y * gridDim.x + blockIdx.x, nwg);
  const int row0 = (wg / gridDim.x) * 128, col0 = (wg % gridDim.x) * 128;
  f32x4 acc[4][4] = {};

  const int srow = t >> 2;
  const int ssl = ((t & 3) ^ ((t >> 3) & 3)) * 8;
  const short* Asrc0 = A + (size_t)(row0 + srow) * K + ssl;
  const short* Asrc1 = A + (size_t)(row0 + 64 + srow) * K + ssl;
  const short* Bsrc0 = Bt + (size_t)(col0 + srow) * K + ssl;
  const short* Bsrc1 = Bt + (size_t)(col0 + 64 + srow) * K + ssl;
  short* AsF = SMEM;
  short* BsF = SMEM + 12288;
  const int wdst = wave * 512;

  const int soA = (quad ^ ((l15 >> 1) & 3)) * 8;

  const int T = K >> 5;   // 24
  gload16(Asrc0, AsF + wdst);
  gload16(Asrc1, AsF + 2048 + wdst);
  gload16(Bsrc0, BsF + wdst);
  gload16(Bsrc1, BsF + 2048 + wdst);
  gload16(Asrc0 + 32, AsF + 4096 + wdst);
  gload16(Asrc1 + 32, AsF + 4096 + 2048 + wdst);

  int ra = 0, wa = 2;
  for (int tt = 0; tt < T; tt++) {
    if (tt + 1 < T) wait2_barrier(); else wait0_barrier();
    if (tt + 1 < T) {
      const int k0 = (tt + 1) * 32;
      short* Bd = BsF + ((tt + 1) & 1) * 4096 + wdst;
      gload16(Bsrc0 + k0, Bd);
      gload16(Bsrc1 + k0, Bd + 2048);
    }
    if (tt + 2 < T) {
      const int k0 = (tt + 2) * 32;
      short* Ad = AsF + wa * 4096 + wdst;
      gload16(Asrc0 + k0, Ad);
      gload16(Asrc1 + k0, Ad + 2048);
    }
    const short* Ab = AsF + ra * 4096;
    const short* Bb = BsF + (tt & 1) * 4096;
    sh8 af[4], bfv[4];
#pragma unroll
    for (int i = 0; i < 4; i++) af[i] = *(const sh8*)&Ab[(wm + i * 16 + l15) * 32 + soA];
#pragma unroll
    for (int j = 0; j < 4; j++) bfv[j] = *(const sh8*)&Bb[(wn + j * 16 + l15) * 32 + soA];
#pragma unroll
    for (int i = 0; i < 4; i++)
#pragma unroll
      for (int j = 0; j < 4; j++)
        acc[i][j] = __builtin_amdgcn_mfma_f32_16x16x32_bf16(af[i], bfv[j], acc[i][j], 0, 0, 0);
    ra = ra == 2 ? 0 : ra + 1;
    wa = wa == 2 ? 0 : wa + 1;
  }

  // s uniform per block: 768 % 128 == 0
  const int s = col0 >= 1536 ? 2 : (col0 >= 768 ? 1 : 0);

  if (s < 2) {
    short* dst = s == 0 ? Qh : Kh;
    // Q scale 1/8 with log2(e) folded (attn uses exp2)
    const float scl = (s == 0) ? 0.18033688011112042f : 1.0f;
#pragma unroll
    for (int j = 0; j < 4; j++) {
      int c = col0 + wn + j * 16 + l15;
      int hd = c - s * 768;           // h*64 + d, uniform h within 16-tile
      int h = hd >> 6;
      float bv = bias[c];
#pragma unroll
      for (int i = 0; i < 4; i++) {
        int rbase = row0 + wm + i * 16 + quad * 4;
#pragma unroll
        for (int e = 0; e < 4; e++) {
          int r = rbase + e;
          int b = r >> 11, n = r & 2047;
          float v = (acc[i][j][e] + bv) * scl;
          dst[(size_t)(b * 12 + h) * 131072 + n * 64 + (hd & 63)] = f2bf(v);
        }
      }
    }
  } else {
    // V: transpose through LDS, write VhT[bh][d][n] coalesced.
    __syncthreads();                 // staging LDS fully consumed
    short* Tl = SMEM;                // [128 c][136] shorts = 34.8KB
#pragma unroll
    for (int j = 0; j < 4; j++) {
      int cl = wn + j * 16 + l15;    // 0..127 (hd offset within block)
      float bv = bias[col0 + cl];
#pragma unroll
      for (int i = 0; i < 4; i++) {
        int rl = wm + i * 16 + quad * 4;   // 0..124, mult of 4
        sh4 pk;
#pragma unroll
        for (int e = 0; e < 4; e++) pk[e] = f2bf(acc[i][j][e] + bv);
        *(sh4*)&Tl[cl * 136 + rl] = pk;
      }
    }
    __syncthreads();
    const int b = row0 >> 11, n0 = row0 & 2047;   // 2048%128==0: same b
    const int h0 = (col0 - 1536) >> 6;
#pragma unroll
    for (int p = 0; p < 8; p++) {
      int cl = (t >> 4) + p * 16;    // 0..127
      int nn = (t & 15) * 8;         // 0..120
      int hg = h0 + (cl >> 6);
      int d = cl & 63;
      sh8 vv = *(const sh8*)&Tl[cl * 136 + nn];
      *(sh8*)&VhT[(size_t)(b * 12 + hg) * 131072 + (size_t)d * 2048 + n0 + nn] = vv;
    }
  }
}

// ---------------- flash attention v9: 512 thr, intra-block key split -------
// 8 waves = 2 groups of 4; group g handles keys [g*1024, g*1024+1024) for
// the same 128 q-rows (wave wl=w&3 owns q-rows wl*32..wl*32+31). Per group:
// attn7 compute (32x32 MFMA, shfl_xor(32) P-exchange) + K 3-buf / V 2-buf
// counted-vmcnt pipeline over 16 iters. Final: group1 ships partial O + l
// through LDS, group0 adds, normalizes, writes. 80KB LDS -> 2 blocks/CU
// = 16 waves/CU (2x the 256-thr version).
__global__ __launch_bounds__(512, 4) void attn9(const short* __restrict__ Qh,
                                                const short* __restrict__ Kh,
                                                const short* __restrict__ VhT,
                                                short* __restrict__ outb) {
  const int bid = blockIdx.x;
  const int qb = bid / 48;          // 0..15
  const int bh = bid - qb * 48;     // 48%8==0: all qb of one bh -> one XCD
  const int t = threadIdx.x;
  const int w = t >> 6, lane = t & 63;
  const int wl = w & 3, g = w >> 2;
  const int l31 = lane & 31, hi = lane >> 5;

  __shared__ short SM[40960];       // per group 20480: K 3x4096, V 2x4096

  const size_t hb = (size_t)bh * 131072;

  // Q fragments (B operand: col=q=l31, k = d = ks*16 + hi*8 + j)
  sh8 qa[4];
  {
    const short* qp = Qh + hb + (size_t)(qb * 128 + wl * 32 + l31) * 64 + hi * 8;
    qa[0] = *(const sh8*)(qp);
    qa[1] = *(const sh8*)(qp + 16);
    qa[2] = *(const sh8*)(qp + 32);
    qa[3] = *(const sh8*)(qp + 48);
  }
  // drain Q loads so in-loop vmcnt counts only staging loads
  asm volatile("s_waitcnt vmcnt(0)" ::: "memory");

  f32x16 o[2] = {};   // O[q=(r&3)+8*(r>>2)+4hi][d=db*32+l31]
  f32x4 lsv = {};     // per-lane partial row-sum, q = l31 (this group's keys)

  // staging: per group 256 thr * 16B = 4KB/call; 2 calls per 64x64 tile
  const int tg = t & 255;
  const int srow = tg >> 3;                      // 0..31
  const int ssl = ((tg & 7) ^ (srow & 7)) * 8;
  const short* Ksrc = Kh + hb + (size_t)(g * 1024 + srow) * 64 + ssl;
  const short* Vsrc = VhT + hb + (size_t)srow * 2048 + g * 1024 + ssl;
  short* KlF = SM + g * 20480;
  short* VtF = KlF + 12288;
  const int wdst = wl * 512;                     // shorts; wave-uniform

  // swizzled fragment slots: logical slot = 2*ks + hi, row&7 == l31&7
  const int sw7 = l31 & 7;
  int rsl[4];
#pragma unroll
  for (int ks = 0; ks < 4; ks++) rsl[ks] = (((ks << 1) | hi) ^ sw7) * 8;

  // prologue: K0, V0, K1 (queue 6; iter0 vmcnt(2) keeps K1's 2)
  gload16(Ksrc, KlF + wdst);
  gload16(Ksrc + (size_t)32 * 64, KlF + 2048 + wdst);
  gload16(Vsrc, VtF + wdst);
  gload16(Vsrc + (size_t)32 * 2048, VtF + 2048 + wdst);
  gload16(Ksrc + (size_t)64 * 64, KlF + 4096 + wdst);
  gload16(Ksrc + (size_t)96 * 64, KlF + 4096 + 2048 + wdst);

  int rk = 0, wk = 2;
  for (int kt = 0; kt < 16; kt++) {
    if (kt < 15) wait2_barrier(); else wait0_barrier();
    if (kt + 1 < 16) {                   // V(t+1), distance 1
      const int key0 = (kt + 1) * 64;
      short* Vd = VtF + ((kt + 1) & 1) * 4096 + wdst;
      gload16(Vsrc + key0, Vd);
      gload16(Vsrc + (size_t)32 * 2048 + key0, Vd + 2048);
    }
    if (kt + 2 < 16) {                   // K(t+2), distance 2
      const int key0 = (kt + 2) * 64;
      short* Kd = KlF + wk * 4096 + wdst;
      gload16(Ksrc + (size_t)key0 * 64, Kd);
      gload16(Ksrc + (size_t)(key0 + 32) * 64, Kd + 2048);
    }

    const short* Kb = KlF + rk * 4096;
    const short* Vb = VtF + (kt & 1) * 4096;

    // QK^T per 32-key block; exp2 + pack + half-wave exchange -> pa[0..3]
    sh8 pa[4];
#pragma unroll
    for (int kb = 0; kb < 2; kb++) {
      const short* kr = Kb + (kb * 32 + l31) * 64;
      f32x16 s = {};
#pragma unroll
      for (int ks = 0; ks < 4; ks++)
        s = __builtin_amdgcn_mfma_f32_32x32x16_bf16(*(const sh8*)(kr + rsl[ks]), qa[ks], s, 0, 0, 0);
      // lane(q=l31, hi) holds keys (reg&3)+8*(reg>>2)+4*hi; u[m] packs
      // regs 2m,2m+1 -> consecutive keys.
      unsigned u[8];
#pragma unroll
      for (int m = 0; m < 8; m++) {
        float e0 = __ocml_native_exp2_f32(s[2 * m]);
        float e1 = __ocml_native_exp2_f32(s[2 * m + 1]);
        lsv[m & 3] += e0 + e1;
        asm("v_cvt_pk_bf16_f32 %0, %1, %2" : "=v"(u[m]) : "v"(e0), "v"(e1));
      }
      // half-wave exchange: pre-select what the partner needs, shfl_xor 32.
      unsigned y0 = (unsigned)__shfl_xor((int)(hi ? u[0] : u[2]), 32, 64);
      unsigned y1 = (unsigned)__shfl_xor((int)(hi ? u[1] : u[3]), 32, 64);
      unsigned y2 = (unsigned)__shfl_xor((int)(hi ? u[4] : u[6]), 32, 64);
      unsigned y3 = (unsigned)__shfl_xor((int)(hi ? u[5] : u[7]), 32, 64);
      unsigned w0 = hi ? y0 : u[0];
      unsigned w1 = hi ? y1 : u[1];
      unsigned w2 = hi ? u[2] : y0;
      unsigned w3 = hi ? u[3] : y1;
      unsigned w4 = hi ? y2 : u[4];
      unsigned w5 = hi ? y3 : u[5];
      unsigned w6 = hi ? u[6] : y2;
      unsigned w7 = hi ? u[7] : y3;
      u32x4 A0 = {w0, w1, w2, w3};
      u32x4 A1 = {w4, w5, w6, w7};
      pa[2 * kb] = __builtin_bit_cast(sh8, A0);
      pa[2 * kb + 1] = __builtin_bit_cast(sh8, A1);
    }

    // O += P @ V
    __builtin_amdgcn_s_setprio(1);
#pragma unroll
    for (int db = 0; db < 2; db++) {
      const short* vr = Vb + (db * 32 + l31) * 64;
#pragma unroll
      for (int ks = 0; ks < 4; ks++)
        o[db] = __builtin_amdgcn_mfma_f32_32x32x16_bf16(pa[ks], *(const sh8*)(vr + rsl[ks]), o[db], 0, 0, 0);
    }
    __builtin_amdgcn_s_setprio(0);
    rk = rk == 2 ? 0 : rk + 1;
    wk = wk == 2 ? 0 : wk + 1;
  }

  // group-partial row-sum: lane holds partial for q=l31; other half lane^32
  float ls = lsv[0] + lsv[1] + lsv[2] + lsv[3];
  ls += __shfl_xor(ls, 32, 64);

  // combine groups: group1 -> LDS -> group0 adds
  __syncthreads();
  float* cb = (float*)SM;
  const int ci = (wl * 64 + lane) * 33;
  if (g == 1) {
#pragma unroll
    for (int r = 0; r < 16; r++) {
      cb[ci + r] = o[0][r];
      cb[ci + 16 + r] = o[1][r];
    }
    cb[ci + 32] = ls;
  }
  __syncthreads();
  if (g == 0) {
#pragma unroll
    for (int r = 0; r < 16; r++) {
      o[0][r] += cb[ci + r];
      o[1][r] += cb[ci + 16 + r];
    }
    ls += cb[ci + 32];
    float inv = 1.f / ls;

    const int b = bh / 12, hh = bh - b * 12;
#pragma unroll
    for (int r = 0; r < 16; r++) {
      int qr = (r & 3) + 8 * (r >> 2) + 4 * hi;
      float iv = __shfl(inv, qr, 64);
      int n = qb * 128 + wl * 32 + qr;
      short* op = outb + (size_t)(b * 2048 + n) * 768 + hh * 64 + l31;
      op[0] = f2bf(o[0][r] * iv);
      op[32] = f2bf(o[1][r] * iv);
    }
  }
}

// ---------------- launcher ----------------
extern "C" void kernel_launch(void* const* d_in, const int* in_sizes, int n_in,
                              void* d_out, int out_size, void* d_ws, size_t ws_size,
                              hipStream_t stream) {
  const float* x = (const float*)d_in[0];
  const float* w_qkv = (const float*)d_in[1];
  const float* b_qkv = (const float*)d_in[2];
  const float* w_proj = (const float*)d_in[3];
  const float* b_proj = (const float*)d_in[4];
  float* out = (float*)d_out;

  char* p = (char*)d_ws;
  short* xb = (short*)p;     p += (size_t)8192 * 768 * 2;    // 12.6 MB
  short* wqkvT = (short*)p;  p += (size_t)2304 * 768 * 2;    // 3.5 MB
  short* wprojT = (short*)p; p += (size_t)768 * 768 * 2;     // 1.2 MB
  short* Qh = (short*)p;     p += (size_t)48 * 131072 * 2;   // 12.6 MB
  short* Kh = (short*)p;     p += (size_t)48 * 131072 * 2;   // 12.6 MB
  short* VhT = (short*)p;    p += (size_t)48 * 131072 * 2;   // 12.6 MB (direct)
  short* attnb = (short*)p;  p += (size_t)8192 * 768 * 2;    // 12.6 MB

  cast_f32_bf16<<<(8192 * 768 / 4) / 256, 256, 0, stream>>>(x, xb, 8192 * 768);
  {
    dim3 gt(2304 / 64, 768 / 64);
    transpose_cast_t<<<gt, 256, 0, stream>>>(w_qkv, wqkvT, 768, 2304);
  }
  {
    dim3 gt(768 / 64, 768 / 64);
    transpose_cast_t<<<gt, 256, 0, stream>>>(w_proj, wprojT, 768, 768);
  }

  dim3 g1(2304 / 128, 8192 / 128);
  gemm_qkv<<<g1, 256, 0, stream>>>(xb, wqkvT, b_qkv, Qh, Kh, VhT);

  attn9<<<16 * 48, 512, 0, stream>>>(Qh, Kh, VhT, attnb);

  dim3 g2(768 / 128, 8192 / 64);
  gemm_bt<1><<<g2, 256, 0, stream>>>(attnb, wprojT, b_proj, out, 8192, 768, 768);
}

// Round 10
// 214.521 us; speedup vs baseline: 1.0378x; 1.0378x over previous
//
#include <hip/hip_runtime.h>

typedef short sh8 __attribute__((ext_vector_type(8)));
typedef short sh4 __attribute__((ext_vector_type(4)));
typedef float f32x4 __attribute__((ext_vector_type(4)));
typedef float f32x16 __attribute__((ext_vector_type(16)));
typedef unsigned u32x4 __attribute__((ext_vector_type(4)));

extern "C" __device__ float __ocml_native_exp2_f32(float);

__device__ __forceinline__ short f2bf(float f) {
  unsigned u = __builtin_bit_cast(unsigned, f);
  u += 0x7fffu + ((u >> 16) & 1u);
  return (short)(u >> 16);
}

// async global->LDS, 16B per lane. LDS dest = wave-uniform base + lane*16.
__device__ __forceinline__ void gload16(const short* g, short* l) {
  __builtin_amdgcn_global_load_lds(
      (const __attribute__((address_space(1))) unsigned*)g,
      (__attribute__((address_space(3))) unsigned*)l, 16, 0, 0);
}

// counted-vmcnt barriers: wait own-wave loads down to N outstanding, then
// block barrier, then compiler memfence (no LDS access hoists above).
__device__ __forceinline__ void wait2_barrier() {
  asm volatile("s_waitcnt vmcnt(2)" ::: "memory");
  __builtin_amdgcn_s_barrier();
  asm volatile("" ::: "memory");
}
__device__ __forceinline__ void wait0_barrier() {
  asm volatile("s_waitcnt vmcnt(0)" ::: "memory");
  __builtin_amdgcn_s_barrier();
  asm volatile("" ::: "memory");
}

// bijective XCD-aware block swizzle (exact for any nwg; 8 XCDs)
__device__ __forceinline__ int xcd_swizzle(int bidl, int nwg) {
  int q = nwg >> 3, rr = nwg & 7;
  int xcd = bidl & 7, idx = bidl >> 3;
  return (xcd < rr ? xcd * (q + 1) : rr * (q + 1) + (xcd - rr) * q) + idx;
}

// ---------------- cast kernels ----------------
__global__ void cast_f32_bf16(const float* __restrict__ in, short* __restrict__ out, int n) {
  int i = (blockIdx.x * blockDim.x + threadIdx.x) * 4;
  if (i >= n) return;
  float4 f = *(const float4*)(in + i);
  sh4 o;
  o.x = f2bf(f.x); o.y = f2bf(f.y); o.z = f2bf(f.z); o.w = f2bf(f.w);
  *(sh4*)(out + i) = o;
}

// in: [K][Nn] fp32 -> out: [Nn][K] bf16. 64x64 tile via LDS: coalesced
// float4 reads, coalesced sh8 writes.
__global__ __launch_bounds__(256) void transpose_cast_t(
    const float* __restrict__ in, short* __restrict__ out, int K, int Nn) {
  __shared__ short Tl[64][72];
  const int t = threadIdx.x;
  const int n0 = blockIdx.x * 64, k0 = blockIdx.y * 64;
  const int kr0 = t >> 4;          // 0..15
  const int nc = (t & 15) * 4;     // 0..60
#pragma unroll
  for (int p = 0; p < 4; p++) {
    int kr = kr0 + p * 16;
    float4 f = *(const float4*)(in + (size_t)(k0 + kr) * Nn + n0 + nc);
    Tl[nc + 0][kr] = f2bf(f.x);
    Tl[nc + 1][kr] = f2bf(f.y);
    Tl[nc + 2][kr] = f2bf(f.z);
    Tl[nc + 3][kr] = f2bf(f.w);
  }
  __syncthreads();
  const int nr0 = t >> 3;          // 0..31
  const int kk = (t & 7) * 8;      // 0..56
#pragma unroll
  for (int p = 0; p < 2; p++) {
    int nr = nr0 + p * 32;
    *(sh8*)(out + (size_t)(n0 + nr) * K + k0 + kk) = *(const sh8*)&Tl[nr][kk];
  }
}

// ---------------- generic GEMM (proj): C[M,Nn] = A @ Bt^T + bias ----------
// 128x128 tile (round-7 proven config). A 3-buf (distance 2) + B 2-buf
// (distance 1, L2-resident weights): 40KB LDS. Per iter: {vmcnt(2); barrier;
// issue B(t+1), A(t+2); compute t}.
template <int OUTF32>
__global__ __launch_bounds__(256, 4) void gemm_bt(
    const short* __restrict__ A, const short* __restrict__ Bt,
    const float* __restrict__ bias, void* __restrict__ Cv,
    int M, int Nn, int K) {
  __shared__ short SMEM[20480];    // A: 3x4096 @0, B: 2x4096 @12288
  const int t = threadIdx.x;
  const int wave = t >> 6, lane = t & 63, quad = lane >> 4, l15 = lane & 15;
  const int wm = (wave >> 1) * 64, wn = (wave & 1) * 64;
  const int nwg = gridDim.x * gridDim.y;
  const int wg = xcd_swizzle(blockIdx.y * gridDim.x + blockIdx.x, nwg);
  const int row0 = (wg / gridDim.x) * 128, col0 = (wg % gridDim.x) * 128;
  f32x4 acc[4][4] = {};

  const int srow = t >> 2;
  const int ssl = ((t & 3) ^ ((t >> 3) & 3)) * 8;
  const short* Asrc0 = A + (size_t)(row0 + srow) * K + ssl;
  const short* Asrc1 = A + (size_t)(row0 + 64 + srow) * K + ssl;
  const short* Bsrc0 = Bt + (size_t)(col0 + srow) * K + ssl;
  const short* Bsrc1 = Bt + (size_t)(col0 + 64 + srow) * K + ssl;
  short* AsF = SMEM;
  short* BsF = SMEM + 12288;
  const int wdst = wave * 512;

  const int soA = (quad ^ ((l15 >> 1) & 3)) * 8;

  const int T = K >> 5;
  // prologue: A0, B0, A1 (queue 6; iter0 vmcnt(2) keeps A1)
  gload16(Asrc0, AsF + wdst);
  gload16(Asrc1, AsF + 2048 + wdst);
  gload16(Bsrc0, BsF + wdst);
  gload16(Bsrc1, BsF + 2048 + wdst);
  gload16(Asrc0 + 32, AsF + 4096 + wdst);
  gload16(Asrc1 + 32, AsF + 4096 + 2048 + wdst);

  int ra = 0, wa = 2;
  for (int tt = 0; tt < T; tt++) {
    if (tt + 1 < T) wait2_barrier(); else wait0_barrier();
    if (tt + 1 < T) {                    // B(t+1), distance 1
      const int k0 = (tt + 1) * 32;
      short* Bd = BsF + ((tt + 1) & 1) * 4096 + wdst;
      gload16(Bsrc0 + k0, Bd);
      gload16(Bsrc1 + k0, Bd + 2048);
    }
    if (tt + 2 < T) {                    // A(t+2), distance 2
      const int k0 = (tt + 2) * 32;
      short* Ad = AsF + wa * 4096 + wdst;
      gload16(Asrc0 + k0, Ad);
      gload16(Asrc1 + k0, Ad + 2048);
    }
    const short* Ab = AsF + ra * 4096;
    const short* Bb = BsF + (tt & 1) * 4096;
    sh8 af[4], bfv[4];
#pragma unroll
    for (int i = 0; i < 4; i++) af[i] = *(const sh8*)&Ab[(wm + i * 16 + l15) * 32 + soA];
#pragma unroll
    for (int j = 0; j < 4; j++) bfv[j] = *(const sh8*)&Bb[(wn + j * 16 + l15) * 32 + soA];
#pragma unroll
    for (int i = 0; i < 4; i++)
#pragma unroll
      for (int j = 0; j < 4; j++)
        acc[i][j] = __builtin_amdgcn_mfma_f32_16x16x32_bf16(af[i], bfv[j], acc[i][j], 0, 0, 0);
    ra = ra == 2 ? 0 : ra + 1;
    wa = wa == 2 ? 0 : wa + 1;
  }

#pragma unroll
  for (int i = 0; i < 4; i++)
#pragma unroll
    for (int j = 0; j < 4; j++) {
      int r = row0 + wm + i * 16 + quad * 4;
      int c = col0 + wn + j * 16 + l15;
      float bv = bias[c];
#pragma unroll
      for (int e = 0; e < 4; e++) {
        float v = acc[i][j][e] + bv;
        if (OUTF32)
          ((float*)Cv)[(size_t)(r + e) * Nn + c] = v;
        else
          ((short*)Cv)[(size_t)(r + e) * Nn + c] = f2bf(v);
      }
    }
}

// ---------------- QKV GEMM with per-head scatter ----------------
// Writes Qh/Kh: [48][2048][64] bf16 and VhT: [48][64][2048] directly
// (V-transpose fused in epilogue). Q gets *(0.125*log2(e)) folded in.
// A3/B2 counted-vmcnt pipeline; 40KB LDS.
__global__ __launch_bounds__(256, 4) void gemm_qkv(
    const short* __restrict__ A, const short* __restrict__ Bt,
    const float* __restrict__ bias,
    short* __restrict__ Qh, short* __restrict__ Kh, short* __restrict__ VhT) {
  const int K = 768;
  __shared__ short SMEM[20480];    // staging 40KB / V-transpose Tl 34.8KB
  const int t = threadIdx.x;
  const int wave = t >> 6, lane = t & 63, quad = lane >> 4, l15 = lane & 15;
  const int wm = (wave >> 1) * 64, wn = (wave & 1) * 64;
  const int nwg = gridDim.x * gridDim.y;     // 18*64, %8==0
  const int wg = xcd_swizzle(blockIdx.y * gridDim.x + blockIdx.x, nwg);
  const int row0 = (wg / gridDim.x) * 128, col0 = (wg % gridDim.x) * 128;
  f32x4 acc[4][4] = {};

  const int srow = t >> 2;
  const int ssl = ((t & 3) ^ ((t >> 3) & 3)) * 8;
  const short* Asrc0 = A + (size_t)(row0 + srow) * K + ssl;
  const short* Asrc1 = A + (size_t)(row0 + 64 + srow) * K + ssl;
  const short* Bsrc0 = Bt + (size_t)(col0 + srow) * K + ssl;
  const short* Bsrc1 = Bt + (size_t)(col0 + 64 + srow) * K + ssl;
  short* AsF = SMEM;
  short* BsF = SMEM + 12288;
  const int wdst = wave * 512;

  const int soA = (quad ^ ((l15 >> 1) & 3)) * 8;

  const int T = K >> 5;   // 24
  gload16(Asrc0, AsF + wdst);
  gload16(Asrc1, AsF + 2048 + wdst);
  gload16(Bsrc0, BsF + wdst);
  gload16(Bsrc1, BsF + 2048 + wdst);
  gload16(Asrc0 + 32, AsF + 4096 + wdst);
  gload16(Asrc1 + 32, AsF + 4096 + 2048 + wdst);

  int ra = 0, wa = 2;
  for (int tt = 0; tt < T; tt++) {
    if (tt + 1 < T) wait2_barrier(); else wait0_barrier();
    if (tt + 1 < T) {
      const int k0 = (tt + 1) * 32;
      short* Bd = BsF + ((tt + 1) & 1) * 4096 + wdst;
      gload16(Bsrc0 + k0, Bd);
      gload16(Bsrc1 + k0, Bd + 2048);
    }
    if (tt + 2 < T) {
      const int k0 = (tt + 2) * 32;
      short* Ad = AsF + wa * 4096 + wdst;
      gload16(Asrc0 + k0, Ad);
      gload16(Asrc1 + k0, Ad + 2048);
    }
    const short* Ab = AsF + ra * 4096;
    const short* Bb = BsF + (tt & 1) * 4096;
    sh8 af[4], bfv[4];
#pragma unroll
    for (int i = 0; i < 4; i++) af[i] = *(const sh8*)&Ab[(wm + i * 16 + l15) * 32 + soA];
#pragma unroll
    for (int j = 0; j < 4; j++) bfv[j] = *(const sh8*)&Bb[(wn + j * 16 + l15) * 32 + soA];
#pragma unroll
    for (int i = 0; i < 4; i++)
#pragma unroll
      for (int j = 0; j < 4; j++)
        acc[i][j] = __builtin_amdgcn_mfma_f32_16x16x32_bf16(af[i], bfv[j], acc[i][j], 0, 0, 0);
    ra = ra == 2 ? 0 : ra + 1;
    wa = wa == 2 ? 0 : wa + 1;
  }

  // s uniform per block: 768 % 128 == 0
  const int s = col0 >= 1536 ? 2 : (col0 >= 768 ? 1 : 0);

  if (s < 2) {
    short* dst = s == 0 ? Qh : Kh;
    // Q scale 1/8 with log2(e) folded (attn uses exp2)
    const float scl = (s == 0) ? 0.18033688011112042f : 1.0f;
#pragma unroll
    for (int j = 0; j < 4; j++) {
      int c = col0 + wn + j * 16 + l15;
      int hd = c - s * 768;           // h*64 + d, uniform h within 16-tile
      int h = hd >> 6;
      float bv = bias[c];
#pragma unroll
      for (int i = 0; i < 4; i++) {
        int rbase = row0 + wm + i * 16 + quad * 4;
#pragma unroll
        for (int e = 0; e < 4; e++) {
          int r = rbase + e;
          int b = r >> 11, n = r & 2047;
          float v = (acc[i][j][e] + bv) * scl;
          dst[(size_t)(b * 12 + h) * 131072 + n * 64 + (hd & 63)] = f2bf(v);
        }
      }
    }
  } else {
    // V: transpose through LDS, write VhT[bh][d][n] coalesced.
    __syncthreads();                 // staging LDS fully consumed
    short* Tl = SMEM;                // [128 c][136] shorts = 34.8KB
#pragma unroll
    for (int j = 0; j < 4; j++) {
      int cl = wn + j * 16 + l15;    // 0..127 (hd offset within block)
      float bv = bias[col0 + cl];
#pragma unroll
      for (int i = 0; i < 4; i++) {
        int rl = wm + i * 16 + quad * 4;   // 0..124, mult of 4
        sh4 pk;
#pragma unroll
        for (int e = 0; e < 4; e++) pk[e] = f2bf(acc[i][j][e] + bv);
        *(sh4*)&Tl[cl * 136 + rl] = pk;
      }
    }
    __syncthreads();
    const int b = row0 >> 11, n0 = row0 & 2047;   // 2048%128==0: same b
    const int h0 = (col0 - 1536) >> 6;
#pragma unroll
    for (int p = 0; p < 8; p++) {
      int cl = (t >> 4) + p * 16;    // 0..127
      int nn = (t & 15) * 8;         // 0..120
      int hg = h0 + (cl >> 6);
      int d = cl & 63;
      sh8 vv = *(const sh8*)&Tl[cl * 136 + nn];
      *(sh8*)&VhT[(size_t)(b * 12 + hg) * 131072 + (size_t)d * 2048 + n0 + nn] = vv;
    }
  }
}

// ---------------- flash attention v10: PV pipelined one tile behind --------
// attn9 structure (512 thr, 2 key-split groups of 4 waves) + software
// pipeline: at iter kt do QK^T(kt) AND PV(kt-1) (independent -> MFMA pipe
// stays fed while exp2/exchange of kt runs on VALU). K 2-buf (write (kt+1)&1,
// read kt&1), V 3-buf (write (kt+1)%3, read (kt-1)%3 - all distinct mod 3).
// vmcnt(2) at every barrier: queue = [V(kt-1)2, K(kt)2, V(kt)2] -> drains
// K(kt)+V(kt-1), keeps V(kt) in flight. Peeled PV(15) after vmcnt(0).
__global__ __launch_bounds__(512, 4) void attn10(const short* __restrict__ Qh,
                                                 const short* __restrict__ Kh,
                                                 const short* __restrict__ VhT,
                                                 short* __restrict__ outb) {
  const int bid = blockIdx.x;
  const int qb = bid / 48;          // 0..15
  const int bh = bid - qb * 48;     // 48%8==0: all qb of one bh -> one XCD
  const int t = threadIdx.x;
  const int w = t >> 6, lane = t & 63;
  const int wl = w & 3, g = w >> 2;
  const int l31 = lane & 31, hi = lane >> 5;

  __shared__ short SM[40960];       // per group 20480: K 2x4096, V 3x4096

  const size_t hb = (size_t)bh * 131072;

  // Q fragments (B operand: col=q=l31, k = d = ks*16 + hi*8 + j)
  sh8 qa[4];
  {
    const short* qp = Qh + hb + (size_t)(qb * 128 + wl * 32 + l31) * 64 + hi * 8;
    qa[0] = *(const sh8*)(qp);
    qa[1] = *(const sh8*)(qp + 16);
    qa[2] = *(const sh8*)(qp + 32);
    qa[3] = *(const sh8*)(qp + 48);
  }
  // drain Q loads so in-loop vmcnt counts only staging loads
  asm volatile("s_waitcnt vmcnt(0)" ::: "memory");

  f32x16 o[2] = {};   // O[q=(r&3)+8*(r>>2)+4hi][d=db*32+l31]
  f32x4 lsv = {};     // per-lane partial row-sum, q = l31 (this group's keys)

  // staging: per group 256 thr * 16B = 4KB/call; 2 calls per 64x64 tile
  const int tg = t & 255;
  const int srow = tg >> 3;                      // 0..31
  const int ssl = ((tg & 7) ^ (srow & 7)) * 8;
  const short* Ksrc = Kh + hb + (size_t)(g * 1024 + srow) * 64 + ssl;
  const short* Vsrc = VhT + hb + (size_t)srow * 2048 + g * 1024 + ssl;
  short* KlF = SM + g * 20480;
  short* VtF = KlF + 8192;
  const int wdst = wl * 512;                     // shorts; wave-uniform

  // swizzled fragment slots: logical slot = 2*ks + hi, row&7 == l31&7
  const int sw7 = l31 & 7;
  int rsl[4];
#pragma unroll
  for (int ks = 0; ks < 4; ks++) rsl[ks] = (((ks << 1) | hi) ^ sw7) * 8;

  // prologue: K0, V0 (queue 4; iter0 vmcnt(2) drains K0, keeps V0)
  gload16(Ksrc, KlF + wdst);
  gload16(Ksrc + (size_t)32 * 64, KlF + 2048 + wdst);
  gload16(Vsrc, VtF + wdst);
  gload16(Vsrc + (size_t)32 * 2048, VtF + 2048 + wdst);

  sh8 pap[4] = {};    // P fragments of the PREVIOUS tile
  int vw = 1;         // V write buf = (kt+1)%3
  int vp = 2;         // V read buf for PV(kt-1) = (kt+2)%3 (valid kt>=1)

  for (int kt = 0; kt < 16; kt++) {
    wait2_barrier();
    if (kt + 1 < 16) {
      // K(kt+1), distance 1 (slack = one full compute phase)
      const int key0 = (kt + 1) * 64;
      short* Kd = KlF + ((kt + 1) & 1) * 4096 + wdst;
      gload16(Ksrc + (size_t)key0 * 64, Kd);
      gload16(Ksrc + (size_t)(key0 + 32) * 64, Kd + 2048);
      // V(kt+1), read lag 2 (consumed at iter kt+2)
      short* Vd = VtF + vw * 4096 + wdst;
      gload16(Vsrc + key0, Vd);
      gload16(Vsrc + (size_t)32 * 2048 + key0, Vd + 2048);
    }

    const short* Kb = KlF + (kt & 1) * 4096;

    // QK^T(kt): per 32-key block MFMA -> exp2 -> cvt_pk (u0/u1)
    unsigned u0[8], u1[8];
#pragma unroll
    for (int kb = 0; kb < 2; kb++) {
      const short* kr = Kb + (kb * 32 + l31) * 64;
      f32x16 s = {};
#pragma unroll
      for (int ks = 0; ks < 4; ks++)
        s = __builtin_amdgcn_mfma_f32_32x32x16_bf16(*(const sh8*)(kr + rsl[ks]), qa[ks], s, 0, 0, 0);
      unsigned* uu = kb ? u1 : u0;
#pragma unroll
      for (int m = 0; m < 8; m++) {
        float e0 = __ocml_native_exp2_f32(s[2 * m]);
        float e1 = __ocml_native_exp2_f32(s[2 * m + 1]);
        lsv[m & 3] += e0 + e1;
        asm("v_cvt_pk_bf16_f32 %0, %1, %2" : "=v"(uu[m]) : "v"(e0), "v"(e1));
      }
    }

    // PV(kt-1): independent of this iteration's QK results -> overlaps
    if (kt > 0) {
      const short* Vb = VtF + vp * 4096;
      __builtin_amdgcn_s_setprio(1);
#pragma unroll
      for (int db = 0; db < 2; db++) {
        const short* vr = Vb + (db * 32 + l31) * 64;
#pragma unroll
        for (int ks = 0; ks < 4; ks++)
          o[db] = __builtin_amdgcn_mfma_f32_32x32x16_bf16(pap[ks], *(const sh8*)(vr + rsl[ks]), o[db], 0, 0, 0);
      }
      __builtin_amdgcn_s_setprio(0);
    }

    // half-wave exchange -> pap (P of tile kt, consumed next iteration)
#pragma unroll
    for (int kb = 0; kb < 2; kb++) {
      const unsigned* uu = kb ? u1 : u0;
      unsigned y0 = (unsigned)__shfl_xor((int)(hi ? uu[0] : uu[2]), 32, 64);
      unsigned y1 = (unsigned)__shfl_xor((int)(hi ? uu[1] : uu[3]), 32, 64);
      unsigned y2 = (unsigned)__shfl_xor((int)(hi ? uu[4] : uu[6]), 32, 64);
      unsigned y3 = (unsigned)__shfl_xor((int)(hi ? uu[5] : uu[7]), 32, 64);
      unsigned w0 = hi ? y0 : uu[0];
      unsigned w1 = hi ? y1 : uu[1];
      unsigned w2 = hi ? uu[2] : y0;
      unsigned w3 = hi ? uu[3] : y1;
      unsigned w4 = hi ? y2 : uu[4];
      unsigned w5 = hi ? y3 : uu[5];
      unsigned w6 = hi ? uu[6] : y2;
      unsigned w7 = hi ? uu[7] : y3;
      u32x4 A0 = {w0, w1, w2, w3};
      u32x4 A1 = {w4, w5, w6, w7};
      pap[2 * kb] = __builtin_bit_cast(sh8, A0);
      pap[2 * kb + 1] = __builtin_bit_cast(sh8, A1);
    }

    vw = vw == 2 ? 0 : vw + 1;
    vp = vp == 2 ? 0 : vp + 1;
  }

  // peeled PV(15): V15 lives in buf 15%3 = 0; drain its loads first
  wait0_barrier();
  {
    const short* Vb = VtF;   // buf 0
#pragma unroll
    for (int db = 0; db < 2; db++) {
      const short* vr = Vb + (db * 32 + l31) * 64;
#pragma unroll
      for (int ks = 0; ks < 4; ks++)
        o[db] = __builtin_amdgcn_mfma_f32_32x32x16_bf16(pap[ks], *(const sh8*)(vr + rsl[ks]), o[db], 0, 0, 0);
    }
  }

  // group-partial row-sum: lane holds partial for q=l31; other half lane^32
  float ls = lsv[0] + lsv[1] + lsv[2] + lsv[3];
  ls += __shfl_xor(ls, 32, 64);

  // combine groups: group1 -> LDS -> group0 adds
  __syncthreads();
  float* cb = (float*)SM;
  const int ci = (wl * 64 + lane) * 33;
  if (g == 1) {
#pragma unroll
    for (int r = 0; r < 16; r++) {
      cb[ci + r] = o[0][r];
      cb[ci + 16 + r] = o[1][r];
    }
    cb[ci + 32] = ls;
  }
  __syncthreads();
  if (g == 0) {
#pragma unroll
    for (int r = 0; r < 16; r++) {
      o[0][r] += cb[ci + r];
      o[1][r] += cb[ci + 16 + r];
    }
    ls += cb[ci + 32];
    float inv = 1.f / ls;

    const int b = bh / 12, hh = bh - b * 12;
#pragma unroll
    for (int r = 0; r < 16; r++) {
      int qr = (r & 3) + 8 * (r >> 2) + 4 * hi;
      float iv = __shfl(inv, qr, 64);
      int n = qb * 128 + wl * 32 + qr;
      short* op = outb + (size_t)(b * 2048 + n) * 768 + hh * 64 + l31;
      op[0] = f2bf(o[0][r] * iv);
      op[32] = f2bf(o[1][r] * iv);
    }
  }
}

// ---------------- launcher ----------------
extern "C" void kernel_launch(void* const* d_in, const int* in_sizes, int n_in,
                              void* d_out, int out_size, void* d_ws, size_t ws_size,
                              hipStream_t stream) {
  const float* x = (const float*)d_in[0];
  const float* w_qkv = (const float*)d_in[1];
  const float* b_qkv = (const float*)d_in[2];
  const float* w_proj = (const float*)d_in[3];
  const float* b_proj = (const float*)d_in[4];
  float* out = (float*)d_out;

  char* p = (char*)d_ws;
  short* xb = (short*)p;     p += (size_t)8192 * 768 * 2;    // 12.6 MB
  short* wqkvT = (short*)p;  p += (size_t)2304 * 768 * 2;    // 3.5 MB
  short* wprojT = (short*)p; p += (size_t)768 * 768 * 2;     // 1.2 MB
  short* Qh = (short*)p;     p += (size_t)48 * 131072 * 2;   // 12.6 MB
  short* Kh = (short*)p;     p += (size_t)48 * 131072 * 2;   // 12.6 MB
  short* VhT = (short*)p;    p += (size_t)48 * 131072 * 2;   // 12.6 MB (direct)
  short* attnb = (short*)p;  p += (size_t)8192 * 768 * 2;    // 12.6 MB

  cast_f32_bf16<<<(8192 * 768 / 4) / 256, 256, 0, stream>>>(x, xb, 8192 * 768);
  {
    dim3 gt(2304 / 64, 768 / 64);
    transpose_cast_t<<<gt, 256, 0, stream>>>(w_qkv, wqkvT, 768, 2304);
  }
  {
    dim3 gt(768 / 64, 768 / 64);
    transpose_cast_t<<<gt, 256, 0, stream>>>(w_proj, wprojT, 768, 768);
  }

  dim3 g1(2304 / 128, 8192 / 128);
  gemm_qkv<<<g1, 256, 0, stream>>>(xb, wqkvT, b_qkv, Qh, Kh, VhT);

  attn10<<<16 * 48, 512, 0, stream>>>(Qh, Kh, VhT, attnb);

  dim3 g2(768 / 128, 8192 / 128);
  gemm_bt<1><<<g2, 256, 0, stream>>>(attnb, wprojT, b_proj, out, 8192, 768, 768);
}